// Round 1
// baseline (12050.901 us; speedup 1.0000x reference)
//
#include <hip/hip_runtime.h>
#include <math.h>

// Swin block: B=16, H=W=96, C=256, WS=6, SH=3, NH=8, N=36, hd=32
// TOK = 16*9216 = 147456 tokens.

#define NTOK 147456
#define LTOK 9216

__device__ __forceinline__ float gelu_exact(float v) {
    return 0.5f * v * (1.0f + erff(v * 0.70710678118654752440f));
}

// ---------------------------------------------------------------------------
// K1: per-window fused shift+partition + QKV + attention (all 8 heads).
// grid = 4096 (B * 256 windows), block = 256.
// writes attnout[tok][c] with tok = b*9216 + win*36 + n (pre-roll flat order)
// ---------------------------------------------------------------------------
__global__ __launch_bounds__(256) void k1_attn(
    const float* __restrict__ x, const float* __restrict__ qkv_w,
    const float* __restrict__ qkv_b, const float* __restrict__ bias_table,
    float* __restrict__ attnout)
{
    __shared__ float xs[36][256];      // 36 KB  window input
    __shared__ float q_s[36][32];      // 4.5 KB
    __shared__ float k_s[36][32];
    __shared__ float v_s[36][32];
    __shared__ float S[36][36];        // 5.1 KB scores

    const int blk = blockIdx.x;
    const int b   = blk >> 8;          // /256
    const int win = blk & 255;
    const int wh  = win >> 4;
    const int ww  = win & 15;
    const int t   = threadIdx.x;

    // gather shifted window: xs[n][c] = x[b][(wh*6+i+3)%96][(ww*6+j+3)%96][c]
    for (int n = 0; n < 36; ++n) {
        const int i = n / 6, j = n % 6;
        const int hs = (wh * 6 + i + 3) % 96;
        const int vs = (ww * 6 + j + 3) % 96;
        xs[n][t] = x[((size_t)b * LTOK + hs * 96 + vs) * 256 + t];
    }
    __syncthreads();

    for (int h = 0; h < 8; ++h) {
        // ---- QKV for this head: 36 x 96 outputs, dot over K=256
        for (int o = t; o < 36 * 96; o += 256) {
            const int n  = o / 96, cc = o % 96;
            const int which = cc >> 5, d = cc & 31;
            const int col = which * 256 + h * 32 + d;
            float acc = qkv_b[col];
            const float* wp = qkv_w + col;
            const float4* xp4 = (const float4*)&xs[n][0];
            #pragma unroll 8
            for (int k4 = 0; k4 < 64; ++k4) {
                const float4 xv = xp4[k4];
                const int k = k4 * 4;
                acc += xv.x * wp[(k    ) * 768];
                acc += xv.y * wp[(k + 1) * 768];
                acc += xv.z * wp[(k + 2) * 768];
                acc += xv.w * wp[(k + 3) * 768];
            }
            if (which == 0)      q_s[n][d] = acc * 5.656854249492380196f;
            else if (which == 1) k_s[n][d] = acc;
            else                 v_s[n][d] = acc;
        }
        __syncthreads();

        // ---- S = q k^T + bias + mask  (36x36)
        for (int o = t; o < 36 * 36; o += 256) {
            const int n = o / 36, m = o % 36;
            float acc = 0.f;
            #pragma unroll
            for (int d = 0; d < 32; ++d) acc += q_s[n][d] * k_s[m][d];
            const int i1 = n / 6, j1 = n % 6, i2 = m / 6, j2 = m % 6;
            const int rel = (i1 - i2 + 5) * 11 + (j1 - j2 + 5);
            acc += bias_table[rel * 8 + h];
            // shift mask: groups differ only in last row/col of windows
            const int hg1 = (wh < 15) ? 0 : ((i1 < 3) ? 1 : 2);
            const int wg1 = (ww < 15) ? 0 : ((j1 < 3) ? 1 : 2);
            const int hg2 = (wh < 15) ? 0 : ((i2 < 3) ? 1 : 2);
            const int wg2 = (ww < 15) ? 0 : ((j2 < 3) ? 1 : 2);
            if (hg1 * 3 + wg1 != hg2 * 3 + wg2) acc -= 100.0f;
            S[n][m] = acc;
        }
        __syncthreads();

        // ---- softmax rows (36 rows, one thread each — tiny)
        if (t < 36) {
            float mx = -1e30f;
            #pragma unroll
            for (int m = 0; m < 36; ++m) mx = fmaxf(mx, S[t][m]);
            float sum = 0.f;
            #pragma unroll
            for (int m = 0; m < 36; ++m) { float e = expf(S[t][m] - mx); S[t][m] = e; sum += e; }
            const float inv = 1.0f / sum;
            #pragma unroll
            for (int m = 0; m < 36; ++m) S[t][m] *= inv;
        }
        __syncthreads();

        // ---- out = P @ v  (36x32) -> attnout
        for (int o = t; o < 36 * 32; o += 256) {
            const int n = o >> 5, d = o & 31;
            float acc = 0.f;
            #pragma unroll
            for (int m = 0; m < 36; ++m) acc += S[n][m] * v_s[m][d];
            attnout[((size_t)blk * 36 + n) * 256 + h * 32 + d] = acc;
        }
        __syncthreads();
    }
}

// ---------------------------------------------------------------------------
// K2: proj GEMM + roll(+3,+3) row-permutation + alpha*shortcut + LN1 -> x1
// grid = NTOK/16 = 9216, block = 256 (thread = output channel)
// ---------------------------------------------------------------------------
__global__ __launch_bounds__(256) void k2_proj_ln(
    const float* __restrict__ attnout, const float* __restrict__ proj_w,
    const float* __restrict__ proj_b, const float* __restrict__ x,
    const float* __restrict__ n1w, const float* __restrict__ n1b,
    float* __restrict__ x1)
{
    __shared__ float a[16][256];   // 16 KB
    const int t = threadIdx.x;
    const int rowbase = blockIdx.x * 16;

    for (int r = 0; r < 16; ++r)
        a[r][t] = attnout[(size_t)(rowbase + r) * 256 + t];
    __syncthreads();

    float acc[16];
    #pragma unroll
    for (int r = 0; r < 16; ++r) acc[r] = 0.f;

    const float* wp = proj_w + t;
    #pragma unroll 4
    for (int k = 0; k < 256; ++k) {
        const float w = wp[k * 256];
        #pragma unroll
        for (int r = 0; r < 16; ++r) acc[r] += a[r][k] * w;
    }
    const float pb = proj_b[t];
    __syncthreads();   // done reading a; reuse it for pre-LN values

    int dst[16];
    #pragma unroll
    for (int r = 0; r < 16; ++r) {
        const int tok = rowbase + r;
        const int b = tok / LTOK, l = tok % LTOK;
        const int hh = l / 96, wwp = l % 96;
        const int l2 = ((hh + 3) % 96) * 96 + ((wwp + 3) % 96);
        const int dtok = b * LTOK + l2;
        dst[r] = dtok;
        const float val = acc[r] + pb + 1.8612097182041991f * x[(size_t)dtok * 256 + t];
        a[r][t] = val;
    }
    __syncthreads();

    const int wv = t >> 6, lane = t & 63;
    for (int r = wv; r < 16; r += 4) {
        const float v0 = a[r][lane], v1 = a[r][lane + 64];
        const float v2 = a[r][lane + 128], v3 = a[r][lane + 192];
        float s  = v0 + v1 + v2 + v3;
        float s2 = v0 * v0 + v1 * v1 + v2 * v2 + v3 * v3;
        #pragma unroll
        for (int off = 32; off >= 1; off >>= 1) {
            s  += __shfl_xor(s, off, 64);
            s2 += __shfl_xor(s2, off, 64);
        }
        const float mu  = s * (1.0f / 256.0f);
        const float var = s2 * (1.0f / 256.0f) - mu * mu;
        const float rstd = rsqrtf(var + 1e-5f);
        float* outp = x1 + (size_t)dst[r] * 256;
        outp[lane      ] = (v0 - mu) * rstd * n1w[lane      ] + n1b[lane      ];
        outp[lane +  64] = (v1 - mu) * rstd * n1w[lane +  64] + n1b[lane +  64];
        outp[lane + 128] = (v2 - mu) * rstd * n1w[lane + 128] + n1b[lane + 128];
        outp[lane + 192] = (v3 - mu) * rstd * n1w[lane + 192] + n1b[lane + 192];
    }
}

// ---------------------------------------------------------------------------
// K3: fc1 + GELU + fc2 + alpha*x1 residual + LN2 -> out
// grid = NTOK/32 = 4608, block = 256; hmid staged 64 cols at a time in LDS
// ---------------------------------------------------------------------------
__global__ __launch_bounds__(256) void k3_mlp(
    const float* __restrict__ x1, const float* __restrict__ fc1_w,
    const float* __restrict__ fc1_b, const float* __restrict__ fc2_w,
    const float* __restrict__ fc2_b, const float* __restrict__ n2w,
    const float* __restrict__ n2b, float* __restrict__ out)
{
    __shared__ float xsm[32][256];   // 32 KB
    __shared__ float hs[32][64];     // 8 KB
    const int t = threadIdx.x;
    const int rowbase = blockIdx.x * 32;

    for (int r = 0; r < 32; ++r)
        xsm[r][t] = x1[(size_t)(rowbase + r) * 256 + t];

    float acc2[32];
    #pragma unroll
    for (int r = 0; r < 32; ++r) acc2[r] = 0.f;
    __syncthreads();

    const int cc = t & 63, rb = t >> 6;   // rb in 0..3

    for (int ch = 0; ch < 16; ++ch) {
        const int col = ch * 64 + cc;
        float acc1[8];
        #pragma unroll
        for (int i = 0; i < 8; ++i) acc1[i] = 0.f;
        const float* w1 = fc1_w + col;
        #pragma unroll 4
        for (int k = 0; k < 256; ++k) {
            const float w = w1[k * 1024];
            #pragma unroll
            for (int i = 0; i < 8; ++i) acc1[i] += xsm[rb * 8 + i][k] * w;
        }
        const float b1 = fc1_b[col];
        __syncthreads();   // previous chunk's fc2 reads of hs are done
        #pragma unroll
        for (int i = 0; i < 8; ++i)
            hs[rb * 8 + i][cc] = gelu_exact(acc1[i] + b1);
        __syncthreads();

        const float* w2 = fc2_w + ch * 64 * 256 + t;
        #pragma unroll 4
        for (int kk = 0; kk < 64; ++kk) {
            const float w = w2[kk * 256];
            #pragma unroll
            for (int r = 0; r < 32; ++r) acc2[r] += hs[r][kk] * w;
        }
    }
    __syncthreads();

    const float b2 = fc2_b[t];
    for (int r = 0; r < 32; ++r)
        xsm[r][t] = acc2[r] + b2 + 1.8612097182041991f * xsm[r][t];
    __syncthreads();

    const int wv = t >> 6, lane = t & 63;
    for (int r = wv; r < 32; r += 4) {
        const float v0 = xsm[r][lane], v1 = xsm[r][lane + 64];
        const float v2 = xsm[r][lane + 128], v3 = xsm[r][lane + 192];
        float s  = v0 + v1 + v2 + v3;
        float s2 = v0 * v0 + v1 * v1 + v2 * v2 + v3 * v3;
        #pragma unroll
        for (int off = 32; off >= 1; off >>= 1) {
            s  += __shfl_xor(s, off, 64);
            s2 += __shfl_xor(s2, off, 64);
        }
        const float mu  = s * (1.0f / 256.0f);
        const float var = s2 * (1.0f / 256.0f) - mu * mu;
        const float rstd = rsqrtf(var + 1e-5f);
        float* outp = out + (size_t)(rowbase + r) * 256;
        outp[lane      ] = (v0 - mu) * rstd * n2w[lane      ] + n2b[lane      ];
        outp[lane +  64] = (v1 - mu) * rstd * n2w[lane +  64] + n2b[lane +  64];
        outp[lane + 128] = (v2 - mu) * rstd * n2w[lane + 128] + n2b[lane + 128];
        outp[lane + 192] = (v3 - mu) * rstd * n2w[lane + 192] + n2b[lane + 192];
    }
}

// ---------------------------------------------------------------------------
extern "C" void kernel_launch(void* const* d_in, const int* in_sizes, int n_in,
                              void* d_out, int out_size, void* d_ws, size_t ws_size,
                              hipStream_t stream)
{
    const float* x          = (const float*)d_in[0];
    const float* qkv_w      = (const float*)d_in[1];
    const float* qkv_b      = (const float*)d_in[2];
    const float* bias_table = (const float*)d_in[3];
    const float* proj_w     = (const float*)d_in[4];
    const float* proj_b     = (const float*)d_in[5];
    const float* n1w        = (const float*)d_in[6];
    const float* n1b        = (const float*)d_in[7];
    const float* n2w        = (const float*)d_in[8];
    const float* n2b        = (const float*)d_in[9];
    const float* fc1_w      = (const float*)d_in[10];
    const float* fc1_b      = (const float*)d_in[11];
    const float* fc2_w      = (const float*)d_in[12];
    const float* fc2_b      = (const float*)d_in[13];
    float* out = (float*)d_out;

    // workspace layout: attnout (151 MB) | x1 (151 MB)
    float* attnout = (float*)d_ws;
    float* x1      = (float*)((char*)d_ws + (size_t)NTOK * 256 * 4);

    k1_attn<<<4096, 256, 0, stream>>>(x, qkv_w, qkv_b, bias_table, attnout);
    k2_proj_ln<<<NTOK / 16, 256, 0, stream>>>(attnout, proj_w, proj_b, x, n1w, n1b, x1);
    k3_mlp<<<NTOK / 32, 256, 0, stream>>>(x1, fc1_w, fc1_b, fc2_w, fc2_b, n2w, n2b, out);
}

// Round 2
// 1404.543 us; speedup vs baseline: 8.5799x; 8.5799x over previous
//
#include <hip/hip_runtime.h>
#include <math.h>

typedef __bf16 bf16x8 __attribute__((ext_vector_type(8)));
typedef float f32x4 __attribute__((ext_vector_type(4)));

#define NTOK 147456
#define LTOK 9216
#define ALPHA 1.8612097182041991f
#define MFMA16(a,b,c) __builtin_amdgcn_mfma_f32_16x16x32_bf16((a),(b),(c),0,0,0)
#define SWB(row,kb) ((kb) ^ ((row)&7))

__device__ __forceinline__ float gelu_exact(float v) {
    return 0.5f * v * (1.0f + erff(v * 0.70710678118654752440f));
}

// ---------------------------------------------------------------------------
// k0: convert weights to bf16, transposed to [out][k] (k contiguous)
// qkvT[768][256], projT[256][256], w1T[1024][256], w2T[256][1024]
// ---------------------------------------------------------------------------
__global__ __launch_bounds__(256) void k0_prep(
    const float* __restrict__ qkv_w, const float* __restrict__ proj_w,
    const float* __restrict__ fc1_w, const float* __restrict__ fc2_w,
    __bf16* __restrict__ qkvT, __bf16* __restrict__ projT,
    __bf16* __restrict__ w1T, __bf16* __restrict__ w2T)
{
    const int id = blockIdx.x * 256 + threadIdx.x;
    if (id < 196608) {
        const int o = id >> 8, k = id & 255;
        qkvT[id] = (__bf16)qkv_w[k * 768 + o];
    } else if (id < 262144) {
        const int i = id - 196608, o = i >> 8, k = i & 255;
        projT[i] = (__bf16)proj_w[k * 256 + o];
    } else if (id < 524288) {
        const int i = id - 262144, o = i >> 8, k = i & 255;
        w1T[i] = (__bf16)fc1_w[k * 1024 + o];
    } else {
        const int i = id - 524288, o = i >> 10, k = i & 1023;
        w2T[i] = (__bf16)fc2_w[k * 256 + o];
    }
}

// ---------------------------------------------------------------------------
// k1: per-window shift+partition (bf16 LDS) + MFMA QKV + fp32 attention
// grid = 4096, block = 256 (4 waves). attnout written bf16.
// ---------------------------------------------------------------------------
__global__ __launch_bounds__(256) void k1_attn(
    const float* __restrict__ x, const __bf16* __restrict__ qkvT,
    const float* __restrict__ qkv_b, const float* __restrict__ bias_table,
    __bf16* __restrict__ attnout)
{
    __shared__ __attribute__((aligned(16))) __bf16 xs[48][256];   // 24 KB swizzled
    __shared__ __attribute__((aligned(16))) __bf16 wtc[96][64];   // 12 KB swizzled
    __shared__ float qkv_s[48][100];  // q(0-31,scaled) k(32-63) v(64-95)
    __shared__ float S[36][40];

    const int blk = blockIdx.x;
    const int b = blk >> 8, win = blk & 255;
    const int wh = win >> 4, ww = win & 15;
    const int t = threadIdx.x;
    const int wid = t >> 6, lane = t & 63;
    const int l15 = lane & 15, lg = lane >> 4;

    // stage shifted window rows 0..35; zero-pad rows 36..47
    for (int o = t; o < 48 * 32; o += 256) {
        const int row = o >> 5, kb = o & 31;
        bf16x8 p;
        if (row < 36) {
            const int i = row / 6, j = row % 6;
            const int gh = (wh * 6 + i + 3) % 96;
            const int gw = (ww * 6 + j + 3) % 96;
            const float* src = x + ((size_t)b * LTOK + gh * 96 + gw) * 256 + kb * 8;
            #pragma unroll
            for (int e = 0; e < 8; ++e) p[e] = (__bf16)src[e];
        } else {
            #pragma unroll
            for (int e = 0; e < 8; ++e) p[e] = (__bf16)0.0f;
        }
        *(bf16x8*)&xs[row][SWB(row, kb) * 8] = p;
    }

    const f32x4 fzero = {0.f, 0.f, 0.f, 0.f};

    for (int h = 0; h < 8; ++h) {
        f32x4 acc[5];
        #pragma unroll
        for (int i = 0; i < 5; ++i) acc[i] = fzero;

        for (int kc = 0; kc < 4; ++kc) {
            __syncthreads();   // prev wtc reads done (and xs staged at h=0,kc=0)
            // stage 96 head-cols x 64 k of qkvT
            for (int o = t; o < 96 * 8; o += 256) {
                const int c = o >> 3, kb = o & 7;
                const int grow = (c >> 5) * 256 + h * 32 + (c & 31);
                *(uint4*)&wtc[c][SWB(c, kb) * 8] =
                    *(const uint4*)(qkvT + (size_t)grow * 256 + kc * 64 + kb * 8);
            }
            __syncthreads();
            #pragma unroll
            for (int i = 0; i < 5; ++i) {
                int tt = wid + 4 * i; if (tt > 17) tt = 17;  // waves 2,3 idle-dup last tile
                const int rt = tt / 6, ct = tt % 6;
                #pragma unroll
                for (int kk = 0; kk < 2; ++kk) {
                    const int arow = rt * 16 + l15;
                    const int kg = kc * 64 + kk * 32 + lg * 8;
                    const bf16x8 a = *(const bf16x8*)&xs[arow][SWB(arow, kg >> 3) * 8];
                    const int brow = ct * 16 + l15;
                    const int kl = kk * 32 + lg * 8;
                    const bf16x8 bb = *(const bf16x8*)&wtc[brow][SWB(brow, kl >> 3) * 8];
                    acc[i] = MFMA16(a, bb, acc[i]);
                }
            }
        }
        __syncthreads();
        // scatter QKV tiles to fp32 LDS (bias, q-scale)
        #pragma unroll
        for (int i = 0; i < 5; ++i) {
            const int tt = wid + 4 * i;
            if (tt < 18) {
                const int rt = tt / 6, ct = tt % 6;
                const int col = ct * 16 + l15;
                const float bias = qkv_b[(col >> 5) * 256 + h * 32 + (col & 31)];
                const float scale = (col < 32) ? 5.656854249492380196f : 1.0f;
                #pragma unroll
                for (int q = 0; q < 4; ++q) {
                    const int row = rt * 16 + lg * 4 + q;
                    qkv_s[row][col] = (acc[i][q] + bias) * scale;
                }
            }
        }
        __syncthreads();
        // S = q k^T + bias + mask
        for (int o = t; o < 36 * 36; o += 256) {
            const int n = o / 36, m = o % 36;
            float a = 0.f;
            #pragma unroll
            for (int d = 0; d < 32; ++d) a += qkv_s[n][d] * qkv_s[m][32 + d];
            const int i1 = n / 6, j1 = n % 6, i2 = m / 6, j2 = m % 6;
            a += bias_table[((i1 - i2 + 5) * 11 + (j1 - j2 + 5)) * 8 + h];
            const int hg1 = (wh < 15) ? 0 : ((i1 < 3) ? 1 : 2);
            const int wg1 = (ww < 15) ? 0 : ((j1 < 3) ? 1 : 2);
            const int hg2 = (wh < 15) ? 0 : ((i2 < 3) ? 1 : 2);
            const int wg2 = (ww < 15) ? 0 : ((j2 < 3) ? 1 : 2);
            if (hg1 * 3 + wg1 != hg2 * 3 + wg2) a -= 100.0f;
            S[n][m] = a;
        }
        __syncthreads();
        // softmax: 4 lanes per row
        if (t < 144) {
            const int r = t >> 2, q4 = t & 3;
            float mx = -1e30f;
            for (int m = q4; m < 36; m += 4) mx = fmaxf(mx, S[r][m]);
            mx = fmaxf(mx, __shfl_xor(mx, 1, 4));
            mx = fmaxf(mx, __shfl_xor(mx, 2, 4));
            float sum = 0.f;
            for (int m = q4; m < 36; m += 4) { const float e = expf(S[r][m] - mx); S[r][m] = e; sum += e; }
            sum += __shfl_xor(sum, 1, 4);
            sum += __shfl_xor(sum, 2, 4);
            const float inv = 1.0f / sum;
            for (int m = q4; m < 36; m += 4) S[r][m] *= inv;
        }
        __syncthreads();
        // PV -> attnout (bf16)
        for (int o = t; o < 36 * 32; o += 256) {
            const int n = o >> 5, d = o & 31;
            float a = 0.f;
            #pragma unroll
            for (int m = 0; m < 36; ++m) a += S[n][m] * qkv_s[m][64 + d];
            attnout[((size_t)blk * 36 + n) * 256 + h * 32 + d] = (__bf16)a;
        }
        // next head's kc=0 barrier orders qkv_s/S reuse
    }
}

// ---------------------------------------------------------------------------
// k2: MFMA proj + roll(+3,+3) permute + alpha*x residual + LN1 -> x1 (fp32)
// grid = 2304, block = 256 (4 waves x 16 rows x 256 cols)
// ---------------------------------------------------------------------------
__global__ __launch_bounds__(256) void k2_proj_ln(
    const __bf16* __restrict__ attnout, const __bf16* __restrict__ projT,
    const float* __restrict__ proj_b, const float* __restrict__ x,
    const float* __restrict__ n1w, const float* __restrict__ n1b,
    float* __restrict__ x1)
{
    __shared__ __attribute__((aligned(16))) __bf16 xs[64][256];   // 32 KB
    __shared__ __attribute__((aligned(16))) __bf16 pwc[256][64];  // 32 KB
    const int t = threadIdx.x;
    const int wid = t >> 6, lane = t & 63;
    const int l15 = lane & 15, lg = lane >> 4;
    const int rowbase = blockIdx.x * 64;
    const int wrow = wid * 16;

    for (int o = t; o < 64 * 32; o += 256) {
        const int row = o >> 5, kb = o & 31;
        *(uint4*)&xs[row][SWB(row, kb) * 8] =
            *(const uint4*)(attnout + (size_t)(rowbase + row) * 256 + kb * 8);
    }

    const f32x4 fzero = {0.f, 0.f, 0.f, 0.f};
    f32x4 acc[16];
    #pragma unroll
    for (int i = 0; i < 16; ++i) acc[i] = fzero;

    for (int kc = 0; kc < 4; ++kc) {
        __syncthreads();
        for (int o = t; o < 256 * 8; o += 256) {
            const int n = o >> 3, kb = o & 7;
            *(uint4*)&pwc[n][SWB(n, kb) * 8] =
                *(const uint4*)(projT + (size_t)n * 256 + kc * 64 + kb * 8);
        }
        __syncthreads();
        #pragma unroll
        for (int kk = 0; kk < 2; ++kk) {
            const int arow = wrow + l15;
            const int kg = kc * 64 + kk * 32 + lg * 8;
            const bf16x8 a = *(const bf16x8*)&xs[arow][SWB(arow, kg >> 3) * 8];
            const int kl = kk * 32 + lg * 8;
            #pragma unroll
            for (int ct = 0; ct < 16; ++ct) {
                const int brow = ct * 16 + l15;
                const bf16x8 bb = *(const bf16x8*)&pwc[brow][SWB(brow, kl >> 3) * 8];
                acc[ct] = MFMA16(a, bb, acc[ct]);
            }
        }
    }

    // epilogue: bias + permuted residual + LN1, write x1 at rolled dst row
    #pragma unroll
    for (int q = 0; q < 4; ++q) {
        const int r = wrow + lg * 4 + q;
        const int tok = rowbase + r;
        const int bb_ = tok / LTOK, l = tok % LTOK;
        const int hh = l / 96, wwp = l % 96;
        const int dtok = bb_ * LTOK + ((hh + 3) % 96) * 96 + ((wwp + 3) % 96);
        const float* xr = x + (size_t)dtok * 256;
        float vals[16];
        float s = 0.f, s2 = 0.f;
        #pragma unroll
        for (int ct = 0; ct < 16; ++ct) {
            const int col = ct * 16 + l15;
            const float v = acc[ct][q] + proj_b[col] + ALPHA * xr[col];
            vals[ct] = v; s += v; s2 += v * v;
        }
        #pragma unroll
        for (int m = 1; m < 16; m <<= 1) {
            s  += __shfl_xor(s,  m, 16);
            s2 += __shfl_xor(s2, m, 16);
        }
        const float mu = s * (1.0f / 256.0f);
        const float var = s2 * (1.0f / 256.0f) - mu * mu;
        const float rstd = rsqrtf(var + 1e-5f);
        float* op = x1 + (size_t)dtok * 256;
        #pragma unroll
        for (int ct = 0; ct < 16; ++ct) {
            const int col = ct * 16 + l15;
            op[col] = (vals[ct] - mu) * rstd * n1w[col] + n1b[col];
        }
    }
}

// ---------------------------------------------------------------------------
// k3: MFMA MLP: fc1+GELU+fc2 + alpha*x1 residual + LN2 -> out
// grid = 1152, block = 512 (8 waves x 16 rows), BM=128, hidden chunk 64
// ---------------------------------------------------------------------------
__global__ __launch_bounds__(512) void k3_mlp(
    const float* __restrict__ x1, const __bf16* __restrict__ w1T,
    const float* __restrict__ fc1_b, const __bf16* __restrict__ w2T,
    const float* __restrict__ fc2_b, const float* __restrict__ n2w,
    const float* __restrict__ n2b, float* __restrict__ out)
{
    __shared__ __attribute__((aligned(16))) __bf16 xs[128][256];  // 64 KB
    __shared__ __attribute__((aligned(16))) __bf16 w1c[64][256];  // 32 KB [hid][k]
    __shared__ __attribute__((aligned(16))) __bf16 hs[128][64];   // 16 KB
    __shared__ __attribute__((aligned(16))) __bf16 w2c[256][64];  // 32 KB [out][k2]

    const int t = threadIdx.x;
    const int wid = t >> 6, lane = t & 63;
    const int l15 = lane & 15, lg = lane >> 4;
    const int rowbase = blockIdx.x * 128;
    const int wrow = wid * 16;

    for (int o = t; o < 128 * 32; o += 512) {
        const int row = o >> 5, kb = o & 31;
        const float* src = x1 + (size_t)(rowbase + row) * 256 + kb * 8;
        bf16x8 p;
        #pragma unroll
        for (int e = 0; e < 8; ++e) p[e] = (__bf16)src[e];
        *(bf16x8*)&xs[row][SWB(row, kb) * 8] = p;
    }

    const f32x4 fzero = {0.f, 0.f, 0.f, 0.f};
    f32x4 acc[16];
    #pragma unroll
    for (int i = 0; i < 16; ++i) acc[i] = fzero;

    for (int ch = 0; ch < 16; ++ch) {
        __syncthreads();   // prev fc2 reads done; xs staged (ch=0)
        for (int o = t; o < 64 * 32; o += 512) {
            const int row = o >> 5, kb = o & 31;
            *(uint4*)&w1c[row][SWB(row, kb) * 8] =
                *(const uint4*)(w1T + (size_t)(ch * 64 + row) * 256 + kb * 8);
        }
        for (int o = t; o < 256 * 8; o += 512) {
            const int n = o >> 3, kb = o & 7;
            *(uint4*)&w2c[n][SWB(n, kb) * 8] =
                *(const uint4*)(w2T + (size_t)n * 1024 + ch * 64 + kb * 8);
        }
        __syncthreads();

        // fc1: 16 rows x 64 cols per wave
        f32x4 acc1[4];
        #pragma unroll
        for (int i = 0; i < 4; ++i) acc1[i] = fzero;
        #pragma unroll
        for (int kk = 0; kk < 8; ++kk) {
            const int arow = wrow + l15;
            const int k0 = kk * 32 + lg * 8;
            const bf16x8 a = *(const bf16x8*)&xs[arow][SWB(arow, k0 >> 3) * 8];
            #pragma unroll
            for (int ct = 0; ct < 4; ++ct) {
                const int brow = ct * 16 + l15;
                const bf16x8 bb = *(const bf16x8*)&w1c[brow][SWB(brow, k0 >> 3) * 8];
                acc1[ct] = MFMA16(a, bb, acc1[ct]);
            }
        }
        // bias + GELU -> hs (bf16, swizzled)
        #pragma unroll
        for (int ct = 0; ct < 4; ++ct) {
            const int col = ct * 16 + l15;
            const float b1 = fc1_b[ch * 64 + col];
            #pragma unroll
            for (int q = 0; q < 4; ++q) {
                const int row = wrow + lg * 4 + q;
                const float v = gelu_exact(acc1[ct][q] + b1);
                hs[row][SWB(row, col >> 3) * 8 + (col & 7)] = (__bf16)v;
            }
        }
        __syncthreads();
        // fc2 accumulate: 16 rows x 256 cols per wave
        #pragma unroll
        for (int kk2 = 0; kk2 < 2; ++kk2) {
            const int arow = wrow + l15;
            const int k0 = kk2 * 32 + lg * 8;
            const bf16x8 a2 = *(const bf16x8*)&hs[arow][SWB(arow, k0 >> 3) * 8];
            #pragma unroll
            for (int ct = 0; ct < 16; ++ct) {
                const int brow = ct * 16 + l15;
                const bf16x8 b2 = *(const bf16x8*)&w2c[brow][SWB(brow, k0 >> 3) * 8];
                acc[ct] = MFMA16(a2, b2, acc[ct]);
            }
        }
    }

    // epilogue: bias + residual + LN2 -> out
    #pragma unroll
    for (int q = 0; q < 4; ++q) {
        const int r = wrow + lg * 4 + q;
        const int tok = rowbase + r;
        const float* xr = x1 + (size_t)tok * 256;
        float vals[16];
        float s = 0.f, s2 = 0.f;
        #pragma unroll
        for (int ct = 0; ct < 16; ++ct) {
            const int col = ct * 16 + l15;
            const float v = acc[ct][q] + fc2_b[col] + ALPHA * xr[col];
            vals[ct] = v; s += v; s2 += v * v;
        }
        #pragma unroll
        for (int m = 1; m < 16; m <<= 1) {
            s  += __shfl_xor(s,  m, 16);
            s2 += __shfl_xor(s2, m, 16);
        }
        const float mu = s * (1.0f / 256.0f);
        const float var = s2 * (1.0f / 256.0f) - mu * mu;
        const float rstd = rsqrtf(var + 1e-5f);
        float* op = out + (size_t)tok * 256;
        #pragma unroll
        for (int ct = 0; ct < 16; ++ct) {
            const int col = ct * 16 + l15;
            op[col] = (vals[ct] - mu) * rstd * n2w[col] + n2b[col];
        }
    }
}

// ---------------------------------------------------------------------------
extern "C" void kernel_launch(void* const* d_in, const int* in_sizes, int n_in,
                              void* d_out, int out_size, void* d_ws, size_t ws_size,
                              hipStream_t stream)
{
    const float* x          = (const float*)d_in[0];
    const float* qkv_w      = (const float*)d_in[1];
    const float* qkv_b      = (const float*)d_in[2];
    const float* bias_table = (const float*)d_in[3];
    const float* proj_w     = (const float*)d_in[4];
    const float* proj_b     = (const float*)d_in[5];
    const float* n1w        = (const float*)d_in[6];
    const float* n1b        = (const float*)d_in[7];
    const float* n2w        = (const float*)d_in[8];
    const float* n2b        = (const float*)d_in[9];
    const float* fc1_w      = (const float*)d_in[10];
    const float* fc1_b      = (const float*)d_in[11];
    const float* fc2_w      = (const float*)d_in[12];
    const float* fc2_b      = (const float*)d_in[13];
    float* out = (float*)d_out;

    // ws layout (bytes):
    char* ws = (char*)d_ws;
    __bf16* attnout = (__bf16*)ws;                                   // 75,497,472
    float*  x1      = (float*)(ws + 75497472);                       // 150,994,944
    __bf16* qkvT    = (__bf16*)(ws + 226492416);                     // 393,216
    __bf16* projT   = (__bf16*)(ws + 226885632);                     // 131,072
    __bf16* w1T     = (__bf16*)(ws + 227016704);                     // 524,288
    __bf16* w2T     = (__bf16*)(ws + 227540992);                     // 524,288

    k0_prep<<<3072, 256, 0, stream>>>(qkv_w, proj_w, fc1_w, fc2_w, qkvT, projT, w1T, w2T);
    k1_attn<<<4096, 256, 0, stream>>>(x, qkvT, qkv_b, bias_table, attnout);
    k2_proj_ln<<<NTOK / 64, 256, 0, stream>>>(attnout, projT, proj_b, x, n1w, n1b, x1);
    k3_mlp<<<NTOK / 128, 512, 0, stream>>>(x1, w1T, fc1_b, w2T, fc2_b, n2w, n2b, out);
}

// Round 3
// 1118.115 us; speedup vs baseline: 10.7779x; 1.2562x over previous
//
#include <hip/hip_runtime.h>
#include <math.h>

typedef __bf16 bf16x8 __attribute__((ext_vector_type(8)));
typedef __bf16 bf16x4 __attribute__((ext_vector_type(4)));
typedef float f32x4 __attribute__((ext_vector_type(4)));

#define NTOK 147456
#define LTOK 9216
#define ALPHA 1.8612097182041991f
#define QSCALE 5.656854249492380196f
#define MFMA16(a,b,c) __builtin_amdgcn_mfma_f32_16x16x32_bf16((a),(b),(c),0,0,0)
#define SWB(row,kb) ((kb) ^ ((row)&7))

__device__ __forceinline__ float gelu_exact(float v) {
    return 0.5f * v * (1.0f + erff(v * 0.70710678118654752440f));
}

// ---------------------------------------------------------------------------
// k0: weights -> bf16 transposed [out][k]
// ---------------------------------------------------------------------------
__global__ __launch_bounds__(256) void k0_prep(
    const float* __restrict__ qkv_w, const float* __restrict__ proj_w,
    const float* __restrict__ fc1_w, const float* __restrict__ fc2_w,
    __bf16* __restrict__ qkvT, __bf16* __restrict__ projT,
    __bf16* __restrict__ w1T, __bf16* __restrict__ w2T)
{
    const int id = blockIdx.x * 256 + threadIdx.x;
    if (id < 196608) {
        const int o = id >> 8, k = id & 255;
        qkvT[id] = (__bf16)qkv_w[k * 768 + o];
    } else if (id < 262144) {
        const int i = id - 196608, o = i >> 8, k = i & 255;
        projT[i] = (__bf16)proj_w[k * 256 + o];
    } else if (id < 524288) {
        const int i = id - 262144, o = i >> 8, k = i & 255;
        w1T[i] = (__bf16)fc1_w[k * 1024 + o];
    } else {
        const int i = id - 524288, o = i >> 10, k = i & 1023;
        w2T[i] = (__bf16)fc2_w[k * 256 + o];
    }
}

// ---------------------------------------------------------------------------
// k1a: QKV GEMM with fused shift+window gather.
// rows in window order r = (b*256+win)*36+n; cols: [0:256)=q*scale+b, k, v
// grid (1152, 3), block 512 (8 waves, wave tile 64x64)
// ---------------------------------------------------------------------------
__global__ __launch_bounds__(512) void k1a_qkv(
    const float* __restrict__ x, const __bf16* __restrict__ qkvT,
    const float* __restrict__ qkv_b, __bf16* __restrict__ qkv)
{
    __shared__ __attribute__((aligned(16))) __bf16 As[128][64];  // 16 KB
    __shared__ __attribute__((aligned(16))) __bf16 Bs[256][64];  // 32 KB
    const int t = threadIdx.x;
    const int wid = t >> 6, lane = t & 63;
    const int l15 = lane & 15, lg = lane >> 4;
    const int mb = blockIdx.x, nb = blockIdx.y;
    const int wm = wid >> 2, wn = wid & 3;

    const f32x4 fzero = {0.f, 0.f, 0.f, 0.f};
    f32x4 acc[4][4];
    #pragma unroll
    for (int i = 0; i < 4; ++i)
        #pragma unroll
        for (int j = 0; j < 4; ++j) acc[i][j] = fzero;

    for (int kc = 0; kc < 4; ++kc) {
        __syncthreads();
        // A: 128 gathered rows x 64 k (fp32 -> bf16)
        for (int o = t; o < 128 * 8; o += 512) {
            const int row = o >> 3, kb = o & 7;
            const int r = mb * 128 + row;
            const int b = r / LTOK, rem = r % LTOK;
            const int w_ = rem / 36, nn = rem % 36;
            const int gh = ((w_ >> 4) * 6 + nn / 6 + 3) % 96;
            const int gw = ((w_ & 15) * 6 + nn % 6 + 3) % 96;
            const float* src = x + ((size_t)b * LTOK + gh * 96 + gw) * 256 + kc * 64 + kb * 8;
            bf16x8 p;
            #pragma unroll
            for (int e = 0; e < 8; ++e) p[e] = (__bf16)src[e];
            *(bf16x8*)&As[row][SWB(row, kb) * 8] = p;
        }
        // B: 256 out-cols x 64 k
        for (int o = t; o < 256 * 8; o += 512) {
            const int row = o >> 3, kb = o & 7;
            *(uint4*)&Bs[row][SWB(row, kb) * 8] =
                *(const uint4*)(qkvT + (size_t)(nb * 256 + row) * 256 + kc * 64 + kb * 8);
        }
        __syncthreads();
        #pragma unroll
        for (int kk = 0; kk < 2; ++kk) {
            bf16x8 af[4], bf_[4];
            #pragma unroll
            for (int rt = 0; rt < 4; ++rt) {
                const int ar = wm * 64 + rt * 16 + l15;
                af[rt] = *(const bf16x8*)&As[ar][((kk * 4 + lg) ^ (ar & 7)) * 8];
            }
            #pragma unroll
            for (int ct = 0; ct < 4; ++ct) {
                const int br = wn * 64 + ct * 16 + l15;
                bf_[ct] = *(const bf16x8*)&Bs[br][((kk * 4 + lg) ^ (br & 7)) * 8];
            }
            #pragma unroll
            for (int rt = 0; rt < 4; ++rt)
                #pragma unroll
                for (int ct = 0; ct < 4; ++ct)
                    acc[rt][ct] = MFMA16(af[rt], bf_[ct], acc[rt][ct]);
        }
    }

    const float scale = (nb == 0) ? QSCALE : 1.0f;
    #pragma unroll
    for (int ct = 0; ct < 4; ++ct) {
        const int col = nb * 256 + wn * 64 + ct * 16 + l15;
        const float bias = qkv_b[col];
        #pragma unroll
        for (int rt = 0; rt < 4; ++rt) {
            #pragma unroll
            for (int q = 0; q < 4; ++q) {
                const int r = mb * 128 + wm * 64 + rt * 16 + lg * 4 + q;
                qkv[(size_t)r * 768 + col] = (__bf16)((acc[rt][ct][q] + bias) * scale);
            }
        }
    }
}

// ---------------------------------------------------------------------------
// k1b: per-window MFMA attention. grid 4096, block 256 (4 waves).
// wave wv handles heads {wv, wv+4}. S via MFMA(K=32), reg softmax
// (deferred normalize), P->LDS, V^T->LDS, PV via MFMA(K=64).
// ---------------------------------------------------------------------------
__global__ __launch_bounds__(256) void k1b_attn(
    const __bf16* __restrict__ qkv, const float* __restrict__ bias_table,
    __bf16* __restrict__ attnout)
{
    __shared__ float bias_s[121][8];                               // 3.9 KB
    __shared__ __attribute__((aligned(16))) __bf16 P[4][48][64];   // 24 KB
    __shared__ __attribute__((aligned(16))) __bf16 vT[4][32][64];  // 16 KB

    const int blk = blockIdx.x;
    const int win = blk & 255;
    const int wh = win >> 4, ww = win & 15;
    const int t = threadIdx.x;
    const int wv = t >> 6, lane = t & 63;
    const int l15 = lane & 15, lg = lane >> 4;
    const size_t rowbase = (size_t)blk * 36;

    for (int o = t; o < 968; o += 256) ((float*)bias_s)[o] = bias_table[o];
    const uint4 z4 = {0u, 0u, 0u, 0u};
    for (int o = t; o < 1536; o += 256) ((uint4*)P)[o] = z4;
    for (int o = t; o < 1024; o += 256) ((uint4*)vT)[o] = z4;
    __syncthreads();

    const f32x4 fzero = {0.f, 0.f, 0.f, 0.f};
    // m-tile (window col) group data, per l15
    int i2_[3], j2_[3], g2_[3];
    #pragma unroll
    for (int ct = 0; ct < 3; ++ct) {
        const int m = ct * 16 + l15;
        const int mm = m < 36 ? m : 35;
        i2_[ct] = mm / 6; j2_[ct] = mm - i2_[ct] * 6;
        const int hg = (wh < 15) ? 0 : (i2_[ct] < 3 ? 1 : 2);
        const int wg = (ww < 15) ? 0 : (j2_[ct] < 3 ? 1 : 2);
        g2_[ct] = hg * 3 + wg;
    }

    for (int hh = 0; hh < 2; ++hh) {
        const int h = hh * 4 + wv;

        // Q/K fragments straight from global
        bf16x8 aq[3], bk[3];
        #pragma unroll
        for (int rt = 0; rt < 3; ++rt) {
            const int n = rt * 16 + l15;
            const int g = n < 36 ? n : 35;
            const __bf16* p = qkv + (rowbase + g) * 768 + h * 32 + lg * 8;
            aq[rt] = *(const bf16x8*)p;
            bk[rt] = *(const bf16x8*)(p + 256);
            if (n >= 36) {
                bf16x8 z;
                #pragma unroll
                for (int e = 0; e < 8; ++e) z[e] = (__bf16)0.0f;
                bk[rt] = z;
            }
        }

        // stage V^T for this head (wave-private slab)
        #pragma unroll
        for (int i = 0; i < 5; ++i) {
            const int idx = i * 64 + lane;
            if (idx < 288) {
                const int m = idx >> 3, d4 = (idx & 7) * 4;
                const bf16x4 vv = *(const bf16x4*)(qkv + (rowbase + m) * 768 + 512 + h * 32 + d4);
                #pragma unroll
                for (int e = 0; e < 4; ++e) {
                    const int d = d4 + e;
                    vT[wv][d][(((m >> 3) ^ (d & 7)) * 8) + (m & 7)] = vv[e];
                }
            }
        }

        // S = Q K^T (9 MFMAs)
        f32x4 s[3][3];
        #pragma unroll
        for (int rt = 0; rt < 3; ++rt)
            #pragma unroll
            for (int ct = 0; ct < 3; ++ct)
                s[rt][ct] = MFMA16(aq[rt], bk[ct], fzero);

        // bias + mask + softmax (deferred normalization)
        float inv_[3][4];
        #pragma unroll
        for (int rt = 0; rt < 3; ++rt) {
            #pragma unroll
            for (int q = 0; q < 4; ++q) {
                const int n0 = rt * 16 + lg * 4 + q;
                const int nn = n0 < 36 ? n0 : 35;
                const int i1 = nn / 6, j1 = nn - i1 * 6;
                const int hg1 = (wh < 15) ? 0 : (i1 < 3 ? 1 : 2);
                const int wg1 = (ww < 15) ? 0 : (j1 < 3 ? 1 : 2);
                const int g1 = hg1 * 3 + wg1;
                #pragma unroll
                for (int ct = 0; ct < 3; ++ct) {
                    const int m = ct * 16 + l15;
                    float val;
                    if (m < 36) {
                        val = s[rt][ct][q] + bias_s[(i1 - i2_[ct] + 5) * 11 + (j1 - j2_[ct] + 5)][h];
                        if (g1 != g2_[ct]) val -= 100.0f;
                    } else {
                        val = -1e30f;
                    }
                    s[rt][ct][q] = val;
                }
                float mx = fmaxf(fmaxf(s[rt][0][q], s[rt][1][q]), s[rt][2][q]);
                mx = fmaxf(mx, __shfl_xor(mx, 1, 16));
                mx = fmaxf(mx, __shfl_xor(mx, 2, 16));
                mx = fmaxf(mx, __shfl_xor(mx, 4, 16));
                mx = fmaxf(mx, __shfl_xor(mx, 8, 16));
                float sum = 0.f;
                #pragma unroll
                for (int ct = 0; ct < 3; ++ct) {
                    const float e = __expf(s[rt][ct][q] - mx);
                    s[rt][ct][q] = e;
                    sum += e;
                }
                sum += __shfl_xor(sum, 1, 16);
                sum += __shfl_xor(sum, 2, 16);
                sum += __shfl_xor(sum, 4, 16);
                sum += __shfl_xor(sum, 8, 16);
                inv_[rt][q] = 1.0f / sum;
            }
        }

        // P -> LDS (bf16, swizzled)
        #pragma unroll
        for (int rt = 0; rt < 3; ++rt)
            #pragma unroll
            for (int q = 0; q < 4; ++q) {
                const int row = rt * 16 + lg * 4 + q;
                #pragma unroll
                for (int ct = 0; ct < 3; ++ct) {
                    const int m = ct * 16 + l15;
                    P[wv][row][(((m >> 3) ^ (row & 7)) * 8) + (m & 7)] = (__bf16)s[rt][ct][q];
                }
            }
        __syncthreads();

        // PV (12 MFMAs, K=64)
        f32x4 ov[3][2];
        #pragma unroll
        for (int rt = 0; rt < 3; ++rt)
            #pragma unroll
            for (int cd = 0; cd < 2; ++cd) ov[rt][cd] = fzero;
        #pragma unroll
        for (int kk = 0; kk < 2; ++kk) {
            bf16x8 pa[3], bv[2];
            #pragma unroll
            for (int rt = 0; rt < 3; ++rt) {
                const int ar = rt * 16 + l15;
                pa[rt] = *(const bf16x8*)&P[wv][ar][((kk * 4 + lg) ^ (ar & 7)) * 8];
            }
            #pragma unroll
            for (int cd = 0; cd < 2; ++cd) {
                const int d = cd * 16 + l15;
                bv[cd] = *(const bf16x8*)&vT[wv][d][((kk * 4 + lg) ^ (d & 7)) * 8];
            }
            #pragma unroll
            for (int rt = 0; rt < 3; ++rt)
                #pragma unroll
                for (int cd = 0; cd < 2; ++cd)
                    ov[rt][cd] = MFMA16(pa[rt], bv[cd], ov[rt][cd]);
        }

        // out = P V * inv
        #pragma unroll
        for (int rt = 0; rt < 3; ++rt)
            #pragma unroll
            for (int cd = 0; cd < 2; ++cd)
                #pragma unroll
                for (int q = 0; q < 4; ++q) {
                    const int n = rt * 16 + lg * 4 + q;
                    if (n < 36)
                        attnout[(rowbase + n) * 256 + h * 32 + cd * 16 + l15] =
                            (__bf16)(ov[rt][cd][q] * inv_[rt][q]);
                }
        __syncthreads();
    }
}

// ---------------------------------------------------------------------------
// k2: MFMA proj + roll(+3,+3) permute + alpha*x residual + LN1 -> x1 (fp32)
// ---------------------------------------------------------------------------
__global__ __launch_bounds__(256) void k2_proj_ln(
    const __bf16* __restrict__ attnout, const __bf16* __restrict__ projT,
    const float* __restrict__ proj_b, const float* __restrict__ x,
    const float* __restrict__ n1w, const float* __restrict__ n1b,
    float* __restrict__ x1)
{
    __shared__ __attribute__((aligned(16))) __bf16 xs[64][256];
    __shared__ __attribute__((aligned(16))) __bf16 pwc[256][64];
    const int t = threadIdx.x;
    const int wid = t >> 6, lane = t & 63;
    const int l15 = lane & 15, lg = lane >> 4;
    const int rowbase = blockIdx.x * 64;
    const int wrow = wid * 16;

    for (int o = t; o < 64 * 32; o += 256) {
        const int row = o >> 5, kb = o & 31;
        *(uint4*)&xs[row][SWB(row, kb) * 8] =
            *(const uint4*)(attnout + (size_t)(rowbase + row) * 256 + kb * 8);
    }

    const f32x4 fzero = {0.f, 0.f, 0.f, 0.f};
    f32x4 acc[16];
    #pragma unroll
    for (int i = 0; i < 16; ++i) acc[i] = fzero;

    for (int kc = 0; kc < 4; ++kc) {
        __syncthreads();
        for (int o = t; o < 256 * 8; o += 256) {
            const int n = o >> 3, kb = o & 7;
            *(uint4*)&pwc[n][SWB(n, kb) * 8] =
                *(const uint4*)(projT + (size_t)n * 256 + kc * 64 + kb * 8);
        }
        __syncthreads();
        #pragma unroll
        for (int kk = 0; kk < 2; ++kk) {
            const int arow = wrow + l15;
            const int kg = kc * 64 + kk * 32 + lg * 8;
            const bf16x8 a = *(const bf16x8*)&xs[arow][SWB(arow, kg >> 3) * 8];
            const int kl = kk * 32 + lg * 8;
            #pragma unroll
            for (int ct = 0; ct < 16; ++ct) {
                const int brow = ct * 16 + l15;
                const bf16x8 bb = *(const bf16x8*)&pwc[brow][SWB(brow, kl >> 3) * 8];
                acc[ct] = MFMA16(a, bb, acc[ct]);
            }
        }
    }

    #pragma unroll
    for (int q = 0; q < 4; ++q) {
        const int r = wrow + lg * 4 + q;
        const int tok = rowbase + r;
        const int bb_ = tok / LTOK, l = tok % LTOK;
        const int hh = l / 96, wwp = l % 96;
        const int dtok = bb_ * LTOK + ((hh + 3) % 96) * 96 + ((wwp + 3) % 96);
        const float* xr = x + (size_t)dtok * 256;
        float vals[16];
        float s = 0.f, s2 = 0.f;
        #pragma unroll
        for (int ct = 0; ct < 16; ++ct) {
            const int col = ct * 16 + l15;
            const float v = acc[ct][q] + proj_b[col] + ALPHA * xr[col];
            vals[ct] = v; s += v; s2 += v * v;
        }
        #pragma unroll
        for (int m = 1; m < 16; m <<= 1) {
            s  += __shfl_xor(s,  m, 16);
            s2 += __shfl_xor(s2, m, 16);
        }
        const float mu = s * (1.0f / 256.0f);
        const float var = s2 * (1.0f / 256.0f) - mu * mu;
        const float rstd = rsqrtf(var + 1e-5f);
        float* op = x1 + (size_t)dtok * 256;
        #pragma unroll
        for (int ct = 0; ct < 16; ++ct) {
            const int col = ct * 16 + l15;
            op[col] = (vals[ct] - mu) * rstd * n1w[col] + n1b[col];
        }
    }
}

// ---------------------------------------------------------------------------
// k3: MFMA MLP fc1+GELU+fc2 + residual + LN2 -> out
// ---------------------------------------------------------------------------
__global__ __launch_bounds__(512) void k3_mlp(
    const float* __restrict__ x1, const __bf16* __restrict__ w1T,
    const float* __restrict__ fc1_b, const __bf16* __restrict__ w2T,
    const float* __restrict__ fc2_b, const float* __restrict__ n2w,
    const float* __restrict__ n2b, float* __restrict__ out)
{
    __shared__ __attribute__((aligned(16))) __bf16 xs[128][256];  // 64 KB
    __shared__ __attribute__((aligned(16))) __bf16 w1c[64][256];  // 32 KB
    __shared__ __attribute__((aligned(16))) __bf16 hs[128][64];   // 16 KB
    __shared__ __attribute__((aligned(16))) __bf16 w2c[256][64];  // 32 KB

    const int t = threadIdx.x;
    const int wid = t >> 6, lane = t & 63;
    const int l15 = lane & 15, lg = lane >> 4;
    const int rowbase = blockIdx.x * 128;
    const int wrow = wid * 16;

    for (int o = t; o < 128 * 32; o += 512) {
        const int row = o >> 5, kb = o & 31;
        const float* src = x1 + (size_t)(rowbase + row) * 256 + kb * 8;
        bf16x8 p;
        #pragma unroll
        for (int e = 0; e < 8; ++e) p[e] = (__bf16)src[e];
        *(bf16x8*)&xs[row][SWB(row, kb) * 8] = p;
    }

    const f32x4 fzero = {0.f, 0.f, 0.f, 0.f};
    f32x4 acc[16];
    #pragma unroll
    for (int i = 0; i < 16; ++i) acc[i] = fzero;

    for (int ch = 0; ch < 16; ++ch) {
        __syncthreads();
        for (int o = t; o < 64 * 32; o += 512) {
            const int row = o >> 5, kb = o & 31;
            *(uint4*)&w1c[row][SWB(row, kb) * 8] =
                *(const uint4*)(w1T + (size_t)(ch * 64 + row) * 256 + kb * 8);
        }
        for (int o = t; o < 256 * 8; o += 512) {
            const int n = o >> 3, kb = o & 7;
            *(uint4*)&w2c[n][SWB(n, kb) * 8] =
                *(const uint4*)(w2T + (size_t)n * 1024 + ch * 64 + kb * 8);
        }
        __syncthreads();

        f32x4 acc1[4];
        #pragma unroll
        for (int i = 0; i < 4; ++i) acc1[i] = fzero;
        #pragma unroll
        for (int kk = 0; kk < 8; ++kk) {
            const int arow = wrow + l15;
            const int k0 = kk * 32 + lg * 8;
            const bf16x8 a = *(const bf16x8*)&xs[arow][SWB(arow, k0 >> 3) * 8];
            #pragma unroll
            for (int ct = 0; ct < 4; ++ct) {
                const int brow = ct * 16 + l15;
                const bf16x8 bb = *(const bf16x8*)&w1c[brow][SWB(brow, k0 >> 3) * 8];
                acc1[ct] = MFMA16(a, bb, acc1[ct]);
            }
        }
        #pragma unroll
        for (int ct = 0; ct < 4; ++ct) {
            const int col = ct * 16 + l15;
            const float b1 = fc1_b[ch * 64 + col];
            #pragma unroll
            for (int q = 0; q < 4; ++q) {
                const int row = wrow + lg * 4 + q;
                const float v = gelu_exact(acc1[ct][q] + b1);
                hs[row][SWB(row, col >> 3) * 8 + (col & 7)] = (__bf16)v;
            }
        }
        __syncthreads();
        #pragma unroll
        for (int kk2 = 0; kk2 < 2; ++kk2) {
            const int arow = wrow + l15;
            const int k0 = kk2 * 32 + lg * 8;
            const bf16x8 a2 = *(const bf16x8*)&hs[arow][SWB(arow, k0 >> 3) * 8];
            #pragma unroll
            for (int ct = 0; ct < 16; ++ct) {
                const int brow = ct * 16 + l15;
                const bf16x8 b2 = *(const bf16x8*)&w2c[brow][SWB(brow, k0 >> 3) * 8];
                acc[ct] = MFMA16(a2, b2, acc[ct]);
            }
        }
    }

    #pragma unroll
    for (int q = 0; q < 4; ++q) {
        const int r = wrow + lg * 4 + q;
        const int tok = rowbase + r;
        const float* xr = x1 + (size_t)tok * 256;
        float vals[16];
        float s = 0.f, s2 = 0.f;
        #pragma unroll
        for (int ct = 0; ct < 16; ++ct) {
            const int col = ct * 16 + l15;
            const float v = acc[ct][q] + fc2_b[col] + ALPHA * xr[col];
            vals[ct] = v; s += v; s2 += v * v;
        }
        #pragma unroll
        for (int m = 1; m < 16; m <<= 1) {
            s  += __shfl_xor(s,  m, 16);
            s2 += __shfl_xor(s2, m, 16);
        }
        const float mu = s * (1.0f / 256.0f);
        const float var = s2 * (1.0f / 256.0f) - mu * mu;
        const float rstd = rsqrtf(var + 1e-5f);
        float* op = out + (size_t)tok * 256;
        #pragma unroll
        for (int ct = 0; ct < 16; ++ct) {
            const int col = ct * 16 + l15;
            op[col] = (vals[ct] - mu) * rstd * n2w[col] + n2b[col];
        }
    }
}

// ---------------------------------------------------------------------------
extern "C" void kernel_launch(void* const* d_in, const int* in_sizes, int n_in,
                              void* d_out, int out_size, void* d_ws, size_t ws_size,
                              hipStream_t stream)
{
    const float* x          = (const float*)d_in[0];
    const float* qkv_w      = (const float*)d_in[1];
    const float* qkv_b      = (const float*)d_in[2];
    const float* bias_table = (const float*)d_in[3];
    const float* proj_w     = (const float*)d_in[4];
    const float* proj_b     = (const float*)d_in[5];
    const float* n1w        = (const float*)d_in[6];
    const float* n1b        = (const float*)d_in[7];
    const float* n2w        = (const float*)d_in[8];
    const float* n2b        = (const float*)d_in[9];
    const float* fc1_w      = (const float*)d_in[10];
    const float* fc1_b      = (const float*)d_in[11];
    const float* fc2_w      = (const float*)d_in[12];
    const float* fc2_b      = (const float*)d_in[13];
    float* out = (float*)d_out;

    char* ws = (char*)d_ws;
    __bf16* qkv     = (__bf16*)ws;                      // 226,492,416 B
    float*  x1      = (float*)ws;                       // overlaps qkv (qkv dead after k1b)
    __bf16* attnout = (__bf16*)(ws + 226492416);        // 75,497,472 B
    __bf16* qkvT    = (__bf16*)(ws + 301989888);        // 393,216 B
    __bf16* projT   = (__bf16*)(ws + 302383104);        // 131,072 B
    __bf16* w1T     = (__bf16*)(ws + 302514176);        // 524,288 B
    __bf16* w2T     = (__bf16*)(ws + 303038464);        // 524,288 B

    k0_prep<<<3072, 256, 0, stream>>>(qkv_w, proj_w, fc1_w, fc2_w, qkvT, projT, w1T, w2T);
    k1a_qkv<<<dim3(1152, 3), 512, 0, stream>>>(x, qkvT, qkv_b, qkv);
    k1b_attn<<<4096, 256, 0, stream>>>(qkv, bias_table, attnout);
    k2_proj_ln<<<NTOK / 64, 256, 0, stream>>>(attnout, projT, proj_b, x, n1w, n1b, x1);
    k3_mlp<<<NTOK / 128, 512, 0, stream>>>(x1, w1T, fc1_b, w2T, fc2_b, n2w, n2b, out);
}